// Round 6
// baseline (891.558 us; speedup 1.0000x reference)
//
#include <hip/hip_runtime.h>

typedef unsigned long long u64;
typedef int i32x4 __attribute__((ext_vector_type(4)));
typedef int i32x16 __attribute__((ext_vector_type(16)));

#define N_SP 3136          // 56*56
#define C_IN 256
#define C_OUT 256
#define BATCH 32
// xsignT: [b][hp 0..57][wp stride 64 (0..57 used)][ci 0..255] int8, zero borders
#define XROW 64
#define XPLANE (58 * XROW * 256)          // per-image bytes = 950272
#define XSIZE ((size_t)BATCH * XPLANE)    // 30,408,704 B

// ---------------------------------------------------------------- weight prep
// One block per output channel o (256 threads = one per input channel).
// wc = w - mean_over_Cin (fp64); A_pack = fragment-ordered sign bytes;
// alpha[o] = mean |clamp(wc,±1)| (fp64). Block 0 zeroes stats.
__global__ __launch_bounds__(256) void prep_weights(const float* __restrict__ w,
                                                    char* __restrict__ A_pack,
                                                    double* __restrict__ alpha,
                                                    u64* __restrict__ stats) {
    const int o = blockIdx.x;
    const int i = threadIdx.x;           // input channel
    const int lane = i & 63, wvid = i >> 6;
    if (o == 0) { stats[i] = 0ull; stats[256 + i] = 0ull; }
    __shared__ double part[4][9];
    __shared__ double part2[4];

    float wv[9];
    const float* wp = w + ((size_t)o * C_IN + i) * 9;
#pragma unroll
    for (int t = 0; t < 9; ++t) wv[t] = wp[t];

    // per-tap block sums via wave shuffles + 4-partial LDS combine
#pragma unroll
    for (int t = 0; t < 9; ++t) {
        double v = (double)wv[t];
#pragma unroll
        for (int off = 32; off > 0; off >>= 1) v += __shfl_down(v, off);
        if (lane == 0) part[wvid][t] = v;
    }
    __syncthreads();

    double asum = 0.0;
#pragma unroll
    for (int t = 0; t < 9; ++t) {
        double mean = (part[0][t] + part[1][t] + part[2][t] + part[3][t]) * (1.0 / 256.0);
        double wc = (double)wv[t] - mean;
        // fragment-order scatter: idx16 = ((t*8 + ci/32)*8 + o/32)*64 + ((ci>>4)&1)*32 + (o&31)
        int idx16 = ((t * 8 + (i >> 5)) * 8 + (o >> 5)) * 64 + (((i >> 4) & 1) << 5) + (o & 31);
        A_pack[(size_t)idx16 * 16 + (i & 15)] = (char)(wc > 0.0 ? 1 : -1);
        double aw = fabs(wc);
        if (aw > 1.0) aw = 1.0;
        asum += aw;
    }
#pragma unroll
    for (int off = 32; off > 0; off >>= 1) asum += __shfl_down(asum, off);
    if (lane == 0) part2[wvid] = asum;
    __syncthreads();
    if (i == 0)
        alpha[o] = (part2[0] + part2[1] + part2[2] + part2[3]) * (1.0 / 2304.0);
}

// ---------------------------------------------------------------- zero xsignT
__global__ __launch_bounds__(256) void zero_xsignT(i32x4* __restrict__ p) {
    p[(size_t)blockIdx.x * 256 + threadIdx.x] = (i32x4){0, 0, 0, 0};
}

// ---------------------------------------------------------------- sign transpose
// grid (49, 32): sp-tile of 64, image b. Reads x[b][ci][sp] coalesced
// (lanes along sp), packs sign bytes, LDS-transposes to channel-last,
// stores 16B/lane coalesced into padded xsignT interior.
__global__ __launch_bounds__(256) void sign_transpose(const float* __restrict__ x,
                                                      char* __restrict__ xsT) {
    const int sp0 = blockIdx.x * 64;
    const int b = blockIdx.y;
    const int lane = threadIdx.x & 63;     // sp within tile
    const int wv = threadIdx.x >> 6;       // ci block of 64
    __shared__ char tile[64 * 272];        // [sp][ci], +16 pad

    const float* xp = x + ((size_t)(b * 256 + (wv << 6))) * N_SP + sp0 + lane;
#pragma unroll
    for (int q = 0; q < 4; ++q) {          // 4 × 16 ci -> 4 × b128 LDS writes
        unsigned d[4];
#pragma unroll
        for (int dd = 0; dd < 4; ++dd) {
            unsigned v = 0;
#pragma unroll
            for (int kk = 0; kk < 4; ++kk) {
                int ci_l = (q << 4) + (dd << 2) + kk;
                float xv = xp[(size_t)ci_l * N_SP];
                v |= (unsigned)(xv > 0.0f ? 0x01u : 0xFFu) << (8 * kk);
            }
            d[dd] = v;
        }
        *(i32x4*)(tile + lane * 272 + (wv << 6) + (q << 4)) =
            (i32x4){(int)d[0], (int)d[1], (int)d[2], (int)d[3]};
    }
    __syncthreads();

    const int t = threadIdx.x;
#pragma unroll
    for (int j = 0; j < 4; ++j) {
        int sp_loc = (j << 4) + (t >> 4);
        int ci0 = (t & 15) << 4;
        i32x4 v = *(const i32x4*)(tile + sp_loc * 272 + ci0);
        int spg = sp0 + sp_loc;
        int h = spg / 56, w = spg - h * 56;
        size_t dst = (((size_t)(b * 58 + h + 1) << 6) + (w + 1)) * 256 + ci0;
        *(i32x4*)(xsT + dst) = v;
    }
}

// ---------------------------------------------------------------- MFMA conv
// grid (1792 = 32b*56h, 2 co-tiles), block 256 = 4 waves.
// Block tile: 128 co x 64 n (one w-row, w 0..63, w>=56 masked).
// Wave (cp = wv>>1, nh = wv&1): 64 co x 32 n via 2 accs sharing each B frag.
// 9 taps x 8 ci-blocks of 32: S = sum of +-1 products, exact in i32.
// Fragment layouts: A/B m|n=lane&31, k=(lane>>5)*16+j; C/D col=lane&31,
// row=(reg&3)+8*(reg>>2)+4*(lane>>5)  [verified shape-determined].
__global__ __launch_bounds__(256, 2) void conv_mfma(const char* __restrict__ xsT,
                                                    const char* __restrict__ A_pack,
                                                    float* __restrict__ out,
                                                    u64* __restrict__ stats) {
    const int tid = threadIdx.x;
    const int lane = tid & 63;
    const int wv = tid >> 6;
    const int l31 = lane & 31, l5 = lane >> 5;
    const int cp = wv >> 1, nh = wv & 1;
    const int r = blockIdx.x;
    const int b = r / 56, h = r - (r / 56) * 56;
    const int coT = blockIdx.y;
    const int co_base = coT * 128 + cp * 64;

    __shared__ char slab[3 * 66 * 272];   // [dh][wp 0..65][ci], ci padded to 272

    // stage 3 source rows (h..h+2 padded) of 64 wp x 256 ci
    {
        const char* src = xsT + ((size_t)(b * 58 + h) << 6) * 256;
        for (int c = tid; c < 3 * 64 * 16; c += 256) {       // 16B chunks
            int dh = c >> 10, rem = c & 1023, wp = rem >> 4, c16 = (rem & 15) << 4;
            *(i32x4*)(slab + (dh * 66 + wp) * 272 + c16) =
                *(const i32x4*)(src + (size_t)dh * (XROW * 256) + wp * 256 + c16);
        }
        for (int c = tid; c < 96; c += 256) {                // zero cols 64,65
            int dh = c >> 5, wp = 64 + ((c >> 4) & 1), c16 = (c & 15) << 4;
            *(i32x4*)(slab + (dh * 66 + wp) * 272 + c16) = (i32x4){0, 0, 0, 0};
        }
    }
    __syncthreads();

    i32x16 acc0 = {0}, acc1 = {0};
    const int col = nh * 32 + l31;        // n (= w)

#pragma unroll
    for (int tap = 0; tap < 9; ++tap) {
        const int dh = tap / 3, dw = tap % 3;
        // A fragments for this tap: 8 ci-blocks x 2 co-halves, coalesced 1KB loads
        i32x4 af[8][2];
#pragma unroll
        for (int cib = 0; cib < 8; ++cib)
#pragma unroll
            for (int a = 0; a < 2; ++a) {
                int co5 = coT * 4 + cp * 2 + a;
                af[cib][a] = *(const i32x4*)(A_pack +
                    ((size_t)(((tap * 8 + cib) * 8 + co5) * 64 + lane) << 4));
            }
        const char* bp = slab + (dh * 66 + col + dw) * 272 + l5 * 16;
#pragma unroll
        for (int cib = 0; cib < 8; ++cib) {
            i32x4 bf = *(const i32x4*)(bp + cib * 32);
            acc0 = __builtin_amdgcn_mfma_i32_32x32x32_i8(af[cib][0], bf, acc0, 0, 0, 0);
            acc1 = __builtin_amdgcn_mfma_i32_32x32x32_i8(af[cib][1], bf, acc1, 0, 0, 0);
        }
    }

    // epilogue: store S as float + per-channel stats
    const int wcol = col;
    const bool valid = (wcol < 56);
#pragma unroll
    for (int a = 0; a < 2; ++a) {
        i32x16 A_ = a ? acc1 : acc0;
#pragma unroll
        for (int reg = 0; reg < 16; ++reg) {
            int S = A_[reg];
            int row = (reg & 3) + 8 * (reg >> 2) + 4 * l5;
            int co = co_base + a * 32 + row;
            if (valid)
                out[((size_t)(b * 256 + co)) * N_SP + h * 56 + wcol] = (float)S;
            int s = valid ? S : 0;
            unsigned sq = (unsigned)(s * s);
#pragma unroll
            for (int off = 16; off > 0; off >>= 1) {
                s += __shfl_xor(s, off);
                sq += (unsigned)__shfl_xor((int)sq, off);
            }
            if (l31 == 0) {
                atomicAdd(&stats[co], (u64)(long long)s);
                atomicAdd(&stats[C_OUT + co], (u64)sq);
            }
        }
    }
}

// ---------------------------------------------------------------- BN consts
__global__ void make_consts(const u64* __restrict__ stats,
                            const double* __restrict__ alpha,
                            const float* __restrict__ gamma,
                            const float* __restrict__ beta,
                            double* __restrict__ AB) {
    const int c = threadIdx.x;
    const double N = (double)(BATCH * N_SP);
    double s1 = (double)(long long)stats[c];
    double s2 = (double)(long long)stats[C_OUT + c];
    double mu = s1 / N;
    double var = s2 / N - mu * mu;
    double a = alpha[c];
    double vy = a * a * var;
    double scale = (double)gamma[c] / sqrt(vy + 1e-5);
    double A = a * scale;
    double B = (double)beta[c] - A * mu;
    AB[c] = A;
    AB[C_OUT + c] = B;
}

// ---------------------------------------------------------------- finalize
// In-place: d_out holds exact-integer S as float; out = (A*S+B > 0) ? 1 : 0.
__global__ __launch_bounds__(256) void finalize(float* __restrict__ out,
                                                const double* __restrict__ AB) {
    const unsigned i4 = blockIdx.x * 256 + threadIdx.x;   // 0 .. 6422527
    const unsigned e = i4 << 2;                            // element base
    const int c = (int)((e / N_SP) & (C_OUT - 1));         // 3136 | 4 -> c uniform in float4
    const double A = AB[c];
    const double B = AB[C_OUT + c];
    float4 v = ((float4*)out)[i4];
    v.x = (A * (double)v.x + B) > 0.0 ? 1.0f : 0.0f;
    v.y = (A * (double)v.y + B) > 0.0 ? 1.0f : 0.0f;
    v.z = (A * (double)v.z + B) > 0.0 ? 1.0f : 0.0f;
    v.w = (A * (double)v.w + B) > 0.0 ? 1.0f : 0.0f;
    ((float4*)out)[i4] = v;
}

// ---------------------------------------------------------------- launch
extern "C" void kernel_launch(void* const* d_in, const int* in_sizes, int n_in,
                              void* d_out, int out_size, void* d_ws, size_t ws_size,
                              hipStream_t stream) {
    const float* x      = (const float*)d_in[0];
    const float* weight = (const float*)d_in[1];
    const float* bias   = (const float*)d_in[2];   (void)bias;  // cancels in BN
    const float* gamma  = (const float*)d_in[3];
    const float* beta   = (const float*)d_in[4];
    float* out = (float*)d_out;

    char* ws = (char*)d_ws;
    u64*    stats = (u64*)(ws);                 // [512]
    double* alpha = (double*)(ws + 4096);       // [256]
    double* AB    = (double*)(ws + 8192);       // [512]
    char*   A_pack = (char*)(ws + 16384);       // 589,824 B fragment-ordered signs
    char*   xsT   = (char*)(ws + (1 << 20));    // 30,408,704 B padded channel-last signs

    prep_weights<<<C_OUT, 256, 0, stream>>>(weight, A_pack, alpha, stats);
    zero_xsignT<<<(int)(XSIZE / 16 / 256), 256, 0, stream>>>((i32x4*)xsT);
    sign_transpose<<<dim3(49, BATCH), 256, 0, stream>>>(x, xsT);
    conv_mfma<<<dim3(BATCH * 56, 2), 256, 0, stream>>>(xsT, A_pack, out, stats);
    make_consts<<<1, C_OUT, 0, stream>>>(stats, alpha, gamma, beta, AB);
    finalize<<<(out_size / 4) / 256, 256, 0, stream>>>(out, AB);
}

// Round 7
// 358.674 us; speedup vs baseline: 2.4857x; 2.4857x over previous
//
#include <hip/hip_runtime.h>

typedef unsigned long long u64;
typedef int i32x4 __attribute__((ext_vector_type(4)));
typedef int i32x16 __attribute__((ext_vector_type(16)));

#define N_SP 3136          // 56*56
#define C_IN 256
#define C_OUT 256
#define BATCH 32
// xsignT: [b][hp 0..57][wp stride 64 (0..57 used)][ci 0..255] int8, zero borders
#define XROW 64
#define XPLANE (58 * XROW * 256)          // per-image bytes = 950272
#define XSIZE ((size_t)BATCH * XPLANE)    // 30,408,704 B

// ---------------------------------------------------------------- weight prep
// One block per output channel o (256 threads = one per input channel).
// wc = w - mean_over_Cin (fp64); A_pack = fragment-ordered sign bytes;
// alpha[o] = mean |clamp(wc,±1)| (fp64).
__global__ __launch_bounds__(256) void prep_weights(const float* __restrict__ w,
                                                    char* __restrict__ A_pack,
                                                    double* __restrict__ alpha) {
    const int o = blockIdx.x;
    const int i = threadIdx.x;           // input channel
    const int lane = i & 63, wvid = i >> 6;
    __shared__ double part[4][9];
    __shared__ double part2[4];

    float wv[9];
    const float* wp = w + ((size_t)o * C_IN + i) * 9;
#pragma unroll
    for (int t = 0; t < 9; ++t) wv[t] = wp[t];

#pragma unroll
    for (int t = 0; t < 9; ++t) {
        double v = (double)wv[t];
#pragma unroll
        for (int off = 32; off > 0; off >>= 1) v += __shfl_down(v, off);
        if (lane == 0) part[wvid][t] = v;
    }
    __syncthreads();

    double asum = 0.0;
#pragma unroll
    for (int t = 0; t < 9; ++t) {
        double mean = (part[0][t] + part[1][t] + part[2][t] + part[3][t]) * (1.0 / 256.0);
        double wc = (double)wv[t] - mean;
        // fragment-order scatter: idx16 = ((t*8 + ci/32)*8 + o/32)*64 + ((ci>>4)&1)*32 + (o&31)
        int idx16 = ((t * 8 + (i >> 5)) * 8 + (o >> 5)) * 64 + (((i >> 4) & 1) << 5) + (o & 31);
        A_pack[(size_t)idx16 * 16 + (i & 15)] = (char)(wc > 0.0 ? 1 : -1);
        double aw = fabs(wc);
        if (aw > 1.0) aw = 1.0;
        asum += aw;
    }
#pragma unroll
    for (int off = 32; off > 0; off >>= 1) asum += __shfl_down(asum, off);
    if (lane == 0) part2[wvid] = asum;
    __syncthreads();
    if (i == 0)
        alpha[o] = (part2[0] + part2[1] + part2[2] + part2[3]) * (1.0 / 2304.0);
}

// ---------------------------------------------------------------- zero xsignT
__global__ __launch_bounds__(256) void zero_xsignT(i32x4* __restrict__ p) {
    p[(size_t)blockIdx.x * 256 + threadIdx.x] = (i32x4){0, 0, 0, 0};
}

// ---------------------------------------------------------------- sign transpose
// grid (49, 32): sp-tile of 64, image b. Reads x[b][ci][sp] coalesced,
// packs sign bytes, LDS-transposes to channel-last, 16B/lane stores.
__global__ __launch_bounds__(256) void sign_transpose(const float* __restrict__ x,
                                                      char* __restrict__ xsT) {
    const int sp0 = blockIdx.x * 64;
    const int b = blockIdx.y;
    const int lane = threadIdx.x & 63;     // sp within tile
    const int wv = threadIdx.x >> 6;       // ci block of 64
    __shared__ char tile[64 * 272];        // [sp][ci], +16 pad

    const float* xp = x + ((size_t)(b * 256 + (wv << 6))) * N_SP + sp0 + lane;
#pragma unroll
    for (int q = 0; q < 4; ++q) {          // 4 × 16 ci -> 4 × b128 LDS writes
        unsigned d[4];
#pragma unroll
        for (int dd = 0; dd < 4; ++dd) {
            unsigned v = 0;
#pragma unroll
            for (int kk = 0; kk < 4; ++kk) {
                int ci_l = (q << 4) + (dd << 2) + kk;
                float xv = xp[(size_t)ci_l * N_SP];
                v |= (unsigned)(xv > 0.0f ? 0x01u : 0xFFu) << (8 * kk);
            }
            d[dd] = v;
        }
        *(i32x4*)(tile + lane * 272 + (wv << 6) + (q << 4)) =
            (i32x4){(int)d[0], (int)d[1], (int)d[2], (int)d[3]};
    }
    __syncthreads();

    const int t = threadIdx.x;
#pragma unroll
    for (int j = 0; j < 4; ++j) {
        int sp_loc = (j << 4) + (t >> 4);
        int ci0 = (t & 15) << 4;
        i32x4 v = *(const i32x4*)(tile + sp_loc * 272 + ci0);
        int spg = sp0 + sp_loc;
        int h = spg / 56, w = spg - h * 56;
        size_t dst = (((size_t)(b * 58 + h + 1) << 6) + (w + 1)) * 256 + ci0;
        *(i32x4*)(xsT + dst) = v;
    }
}

// ---------------------------------------------------------------- MFMA conv
// grid 1792 = 32b*56h, block 256 = 4 waves. Block tile: 256 co x 64 n (one
// output row; w>=56 masked). Wave wv: co 64wv..64wv+63 (2 co-blocks of 32)
// x 64 n (2 n-halves) = 4 accumulators; A fragments reused across n-halves.
// Epilogue is pure coalesced stores — R6's shuffle+atomic epilogue (1.8M
// atomics onto 512 addresses) serialized at L2 and idled both pipes.
// Fragment layouts (verified R6, absmax 0): A/B m|n=lane&31, k=(lane>>5)*16+j;
// C/D col=lane&31, row=(reg&3)+8*(reg>>2)+4*(lane>>5).
__global__ __launch_bounds__(256, 2) void conv_mfma(const char* __restrict__ xsT,
                                                    const char* __restrict__ A_pack,
                                                    float* __restrict__ out) {
    const int tid = threadIdx.x;
    const int lane = tid & 63;
    const int wv = tid >> 6;
    const int l31 = lane & 31, l5 = lane >> 5;
    const int r = blockIdx.x;
    const int b = r / 56, h = r - (r / 56) * 56;

    __shared__ char slab[3 * 66 * 272];   // [dh][wp 0..65][ci], ci padded to 272

    // stage 3 source rows (h..h+2 padded) of 64 wp x 256 ci
    {
        const char* src = xsT + ((size_t)(b * 58 + h) << 6) * 256;
        for (int c = tid; c < 3 * 64 * 16; c += 256) {       // 16B chunks
            int dh = c >> 10, rem = c & 1023, wp = rem >> 4, c16 = (rem & 15) << 4;
            *(i32x4*)(slab + (dh * 66 + wp) * 272 + c16) =
                *(const i32x4*)(src + (size_t)dh * (XROW * 256) + wp * 256 + c16);
        }
        for (int c = tid; c < 96; c += 256) {                // zero cols 64,65
            int dh = c >> 5, wp = 64 + ((c >> 4) & 1), c16 = (c & 15) << 4;
            *(i32x4*)(slab + (dh * 66 + wp) * 272 + c16) = (i32x4){0, 0, 0, 0};
        }
    }
    __syncthreads();

    i32x16 acc00 = {0}, acc01 = {0}, acc10 = {0}, acc11 = {0};

#pragma unroll
    for (int tap = 0; tap < 9; ++tap) {
        const int dh = tap / 3, dw = tap % 3;
        // A fragments: 8 ci-blocks x 2 co-blocks (co5 = wv*2+a), 1KB coalesced
        i32x4 af[8][2];
#pragma unroll
        for (int cib = 0; cib < 8; ++cib)
#pragma unroll
            for (int a = 0; a < 2; ++a)
                af[cib][a] = *(const i32x4*)(A_pack +
                    ((size_t)(((tap * 8 + cib) * 8 + wv * 2 + a) * 64 + lane) << 4));
        const char* bp0 = slab + (dh * 66 + l31 + dw) * 272 + l5 * 16;
        const char* bp1 = bp0 + 32 * 272;
#pragma unroll
        for (int cib = 0; cib < 8; ++cib) {
            i32x4 bf0 = *(const i32x4*)(bp0 + cib * 32);
            i32x4 bf1 = *(const i32x4*)(bp1 + cib * 32);
            acc00 = __builtin_amdgcn_mfma_i32_32x32x32_i8(af[cib][0], bf0, acc00, 0, 0, 0);
            acc01 = __builtin_amdgcn_mfma_i32_32x32x32_i8(af[cib][0], bf1, acc01, 0, 0, 0);
            acc10 = __builtin_amdgcn_mfma_i32_32x32x32_i8(af[cib][1], bf0, acc10, 0, 0, 0);
            acc11 = __builtin_amdgcn_mfma_i32_32x32x32_i8(af[cib][1], bf1, acc11, 0, 0, 0);
        }
    }

    // epilogue: pure stores (S exact integer as float)
    float* ob = out + ((size_t)(b * 256 + wv * 64)) * N_SP + h * 56;
#pragma unroll
    for (int a = 0; a < 2; ++a)
#pragma unroll
        for (int nh = 0; nh < 2; ++nh) {
            const i32x16 A_ = (a == 0) ? (nh == 0 ? acc00 : acc01)
                                       : (nh == 0 ? acc10 : acc11);
            const int w = nh * 32 + l31;
            if (w < 56) {
#pragma unroll
                for (int reg = 0; reg < 16; ++reg) {
                    int row = (reg & 3) + 8 * (reg >> 2) + 4 * l5;
                    ob[(size_t)(a * 32 + row) * N_SP + w] = (float)A_[reg];
                }
            }
        }
}

// ---------------------------------------------------------------- stats
// One block per channel: exact i64/u64 reduction of S over all b,sp.
// No atomics — single writer per stats slot.
__global__ __launch_bounds__(256) void stats_reduce(const float* __restrict__ out,
                                                    u64* __restrict__ stats) {
    const int c = blockIdx.x;
    const int t = threadIdx.x;
    long long s1 = 0;
    u64 s2 = 0;
    for (int i = t; i < BATCH * 784; i += 256) {
        int b = i / 784, q = i - b * 784;
        float4 v = ((const float4*)out)[(size_t)(b * 256 + c) * 784 + q];
        int x0 = (int)v.x, x1 = (int)v.y, x2 = (int)v.z, x3 = (int)v.w;
        s1 += x0 + x1 + x2 + x3;
        s2 += (u64)((long long)x0 * x0 + (long long)x1 * x1 +
                    (long long)x2 * x2 + (long long)x3 * x3);
    }
#pragma unroll
    for (int off = 32; off > 0; off >>= 1) {
        s1 += __shfl_down(s1, off);
        s2 += __shfl_down(s2, off);
    }
    __shared__ long long p1[4];
    __shared__ u64 p2[4];
    if ((t & 63) == 0) { p1[t >> 6] = s1; p2[t >> 6] = s2; }
    __syncthreads();
    if (t == 0) {
        stats[c] = (u64)(p1[0] + p1[1] + p1[2] + p1[3]);
        stats[C_OUT + c] = p2[0] + p2[1] + p2[2] + p2[3];
    }
}

// ---------------------------------------------------------------- BN consts
__global__ void make_consts(const u64* __restrict__ stats,
                            const double* __restrict__ alpha,
                            const float* __restrict__ gamma,
                            const float* __restrict__ beta,
                            double* __restrict__ AB) {
    const int c = threadIdx.x;
    const double N = (double)(BATCH * N_SP);
    double s1 = (double)(long long)stats[c];
    double s2 = (double)(long long)stats[C_OUT + c];
    double mu = s1 / N;
    double var = s2 / N - mu * mu;
    double a = alpha[c];
    double vy = a * a * var;
    double scale = (double)gamma[c] / sqrt(vy + 1e-5);
    double A = a * scale;
    double B = (double)beta[c] - A * mu;
    AB[c] = A;
    AB[C_OUT + c] = B;
}

// ---------------------------------------------------------------- finalize
// In-place: d_out holds exact-integer S as float; out = (A*S+B > 0) ? 1 : 0.
__global__ __launch_bounds__(256) void finalize(float* __restrict__ out,
                                                const double* __restrict__ AB) {
    const unsigned i4 = blockIdx.x * 256 + threadIdx.x;   // 0 .. 6422527
    const unsigned e = i4 << 2;                            // element base
    const int c = (int)((e / N_SP) & (C_OUT - 1));         // 3136 | 4 -> c uniform in float4
    const double A = AB[c];
    const double B = AB[C_OUT + c];
    float4 v = ((float4*)out)[i4];
    v.x = (A * (double)v.x + B) > 0.0 ? 1.0f : 0.0f;
    v.y = (A * (double)v.y + B) > 0.0 ? 1.0f : 0.0f;
    v.z = (A * (double)v.z + B) > 0.0 ? 1.0f : 0.0f;
    v.w = (A * (double)v.w + B) > 0.0 ? 1.0f : 0.0f;
    ((float4*)out)[i4] = v;
}

// ---------------------------------------------------------------- launch
extern "C" void kernel_launch(void* const* d_in, const int* in_sizes, int n_in,
                              void* d_out, int out_size, void* d_ws, size_t ws_size,
                              hipStream_t stream) {
    const float* x      = (const float*)d_in[0];
    const float* weight = (const float*)d_in[1];
    const float* bias   = (const float*)d_in[2];   (void)bias;  // cancels in BN
    const float* gamma  = (const float*)d_in[3];
    const float* beta   = (const float*)d_in[4];
    float* out = (float*)d_out;

    char* ws = (char*)d_ws;
    u64*    stats = (u64*)(ws);                 // [512]
    double* alpha = (double*)(ws + 4096);       // [256]
    double* AB    = (double*)(ws + 8192);       // [512]
    char*   A_pack = (char*)(ws + 16384);       // 589,824 B fragment-ordered signs
    char*   xsT   = (char*)(ws + (1 << 20));    // 30,408,704 B padded channel-last signs

    prep_weights<<<C_OUT, 256, 0, stream>>>(weight, A_pack, alpha);
    zero_xsignT<<<(int)(XSIZE / 16 / 256), 256, 0, stream>>>((i32x4*)xsT);
    sign_transpose<<<dim3(49, BATCH), 256, 0, stream>>>(x, xsT);
    conv_mfma<<<BATCH * 56, 256, 0, stream>>>(xsT, A_pack, out);
    stats_reduce<<<C_OUT, 256, 0, stream>>>(out, stats);
    make_consts<<<1, C_OUT, 0, stream>>>(stats, alpha, gamma, beta, AB);
    finalize<<<(out_size / 4) / 256, 256, 0, stream>>>(out, AB);
}

// Round 8
// 357.400 us; speedup vs baseline: 2.4946x; 1.0036x over previous
//
#include <hip/hip_runtime.h>

typedef unsigned long long u64;
typedef int i32x4 __attribute__((ext_vector_type(4)));
typedef int i32x16 __attribute__((ext_vector_type(16)));

#define N_SP 3136          // 56*56
#define C_IN 256
#define C_OUT 256
#define BATCH 32
// xsignT: [b][hp 0..57][wp stride 64 (0..57 used)][ci 0..255] int8, zero borders
#define XROW 64
#define XPLANE (58 * XROW * 256)          // per-image bytes = 950272
#define XSIZE ((size_t)BATCH * XPLANE)    // 30,408,704 B

// ---------------------------------------------------------------- weight prep
// One block per output channel o (256 threads = one per input channel).
// wc = w - mean_over_Cin (fp64); A_pack = fragment-ordered sign bytes;
// alpha[o] = mean |clamp(wc,±1)| (fp64). Block 0 zeroes stats (stats_reduce
// accumulates atomically later in the stream).
__global__ __launch_bounds__(256) void prep_weights(const float* __restrict__ w,
                                                    char* __restrict__ A_pack,
                                                    double* __restrict__ alpha,
                                                    u64* __restrict__ stats) {
    const int o = blockIdx.x;
    const int i = threadIdx.x;           // input channel
    const int lane = i & 63, wvid = i >> 6;
    if (o == 0) { stats[i] = 0ull; stats[256 + i] = 0ull; }
    __shared__ double part[4][9];
    __shared__ double part2[4];

    float wv[9];
    const float* wp = w + ((size_t)o * C_IN + i) * 9;
#pragma unroll
    for (int t = 0; t < 9; ++t) wv[t] = wp[t];

#pragma unroll
    for (int t = 0; t < 9; ++t) {
        double v = (double)wv[t];
#pragma unroll
        for (int off = 32; off > 0; off >>= 1) v += __shfl_down(v, off);
        if (lane == 0) part[wvid][t] = v;
    }
    __syncthreads();

    double asum = 0.0;
#pragma unroll
    for (int t = 0; t < 9; ++t) {
        double mean = (part[0][t] + part[1][t] + part[2][t] + part[3][t]) * (1.0 / 256.0);
        double wc = (double)wv[t] - mean;
        // fragment-order scatter: idx16 = ((t*8 + ci/32)*8 + o/32)*64 + ((ci>>4)&1)*32 + (o&31)
        int idx16 = ((t * 8 + (i >> 5)) * 8 + (o >> 5)) * 64 + (((i >> 4) & 1) << 5) + (o & 31);
        A_pack[(size_t)idx16 * 16 + (i & 15)] = (char)(wc > 0.0 ? 1 : -1);
        double aw = fabs(wc);
        if (aw > 1.0) aw = 1.0;
        asum += aw;
    }
#pragma unroll
    for (int off = 32; off > 0; off >>= 1) asum += __shfl_down(asum, off);
    if (lane == 0) part2[wvid] = asum;
    __syncthreads();
    if (i == 0)
        alpha[o] = (part2[0] + part2[1] + part2[2] + part2[3]) * (1.0 / 2304.0);
}

// ---------------------------------------------------------------- zero borders
// Interior (hp 1..56, wp 1..56) is fully overwritten by sign_transpose; only
// the border strips need zeroing: rows hp∈{0,57} (all wp) + cols wp∈{0,57..63}
// for hp 1..56. 9216 16B-chunks per image, 294912 total -> 1152 blocks.
__global__ __launch_bounds__(256) void zero_borders(char* __restrict__ xsT) {
    const int tid = blockIdx.x * 256 + threadIdx.x;   // 0 .. 294911
    const int b = tid / 9216;
    const int r = tid - b * 9216;
    int hp, wp, c16;
    if (r < 2048) {                       // full rows 0 and 57
        hp = (r >> 10) * 57;
        wp = (r >> 4) & 63;
        c16 = (r & 15) << 4;
    } else {                              // cols 0, 57..63 of rows 1..56
        int r2 = r - 2048;
        hp = 1 + (r2 >> 7);
        int q = r2 & 127;
        int wi = q >> 4;
        wp = (wi == 0) ? 0 : 56 + wi;
        c16 = (q & 15) << 4;
    }
    *(i32x4*)(xsT + (((size_t)(b * 58 + hp) << 6) + wp) * 256 + c16) = (i32x4){0, 0, 0, 0};
}

// ---------------------------------------------------------------- sign transpose
// grid (49, 32): sp-tile of 64, image b. Reads x[b][ci][sp] coalesced,
// packs sign bytes, LDS-transposes to channel-last, 16B/lane stores.
__global__ __launch_bounds__(256) void sign_transpose(const float* __restrict__ x,
                                                      char* __restrict__ xsT) {
    const int sp0 = blockIdx.x * 64;
    const int b = blockIdx.y;
    const int lane = threadIdx.x & 63;     // sp within tile
    const int wv = threadIdx.x >> 6;       // ci block of 64
    __shared__ char tile[64 * 272];        // [sp][ci], +16 pad

    const float* xp = x + ((size_t)(b * 256 + (wv << 6))) * N_SP + sp0 + lane;
#pragma unroll
    for (int q = 0; q < 4; ++q) {          // 4 × 16 ci -> 4 × b128 LDS writes
        unsigned d[4];
#pragma unroll
        for (int dd = 0; dd < 4; ++dd) {
            unsigned v = 0;
#pragma unroll
            for (int kk = 0; kk < 4; ++kk) {
                int ci_l = (q << 4) + (dd << 2) + kk;
                float xv = xp[(size_t)ci_l * N_SP];
                v |= (unsigned)(xv > 0.0f ? 0x01u : 0xFFu) << (8 * kk);
            }
            d[dd] = v;
        }
        *(i32x4*)(tile + lane * 272 + (wv << 6) + (q << 4)) =
            (i32x4){(int)d[0], (int)d[1], (int)d[2], (int)d[3]};
    }
    __syncthreads();

    const int t = threadIdx.x;
#pragma unroll
    for (int j = 0; j < 4; ++j) {
        int sp_loc = (j << 4) + (t >> 4);
        int ci0 = (t & 15) << 4;
        i32x4 v = *(const i32x4*)(tile + sp_loc * 272 + ci0);
        int spg = sp0 + sp_loc;
        int h = spg / 56, w = spg - h * 56;
        size_t dst = (((size_t)(b * 58 + h + 1) << 6) + (w + 1)) * 256 + ci0;
        *(i32x4*)(xsT + dst) = v;
    }
}

// ---------------------------------------------------------------- MFMA conv
// grid 896 = 32b * 28 row-pairs, block 256 = 4 waves. Block tile: 256 co x
// 2 rows x 64 n. Wave wv: co 64wv..64wv+63, both rows, both n-halves = 8 accs.
// A fragments shared across rows AND n-halves: per cib, 6 loads feed 8 MFMAs
// (R7: 6 loads per 4 MFMAs -> ds latency diluted the matrix pipe to 22%).
// Staging amortized 2x (4 input rows serve 2 output rows).
// Fragment layouts (verified R6/R7, absmax 0): A/B m|n=lane&31, k=(lane>>5)*16+j;
// C/D col=lane&31, row=(reg&3)+8*(reg>>2)+4*(lane>>5).
__global__ __launch_bounds__(256, 2) void conv_mfma(const char* __restrict__ xsT,
                                                    const char* __restrict__ A_pack,
                                                    float* __restrict__ out) {
    const int tid = threadIdx.x;
    const int lane = tid & 63;
    const int wv = tid >> 6;
    const int l31 = lane & 31, l5 = lane >> 5;
    const int blk = blockIdx.x;
    const int b = blk / 28;
    const int h0 = (blk - b * 28) * 2;

    __shared__ char slab[4 * 66 * 272];   // [dh 0..3][wp 0..65][ci], ci padded to 272

    // stage 4 source rows (padded h0..h0+3) of 64 wp x 256 ci
    {
        const char* src = xsT + ((size_t)(b * 58 + h0) << 6) * 256;
        for (int c = tid; c < 4 * 64 * 16; c += 256) {       // 16B chunks
            int dh = c >> 10, rem = c & 1023, wp = rem >> 4, c16 = (rem & 15) << 4;
            *(i32x4*)(slab + (dh * 66 + wp) * 272 + c16) =
                *(const i32x4*)(src + (size_t)dh * (XROW * 256) + wp * 256 + c16);
        }
        for (int c = tid; c < 128; c += 256) {               // zero cols 64,65
            int dh = c >> 5, wp = 64 + ((c >> 4) & 1), c16 = (c & 15) << 4;
            *(i32x4*)(slab + (dh * 66 + wp) * 272 + c16) = (i32x4){0, 0, 0, 0};
        }
    }
    __syncthreads();

    i32x16 acc[2][2][2] = {};   // [a co-block][nh][row]

#pragma unroll
    for (int tap = 0; tap < 9; ++tap) {
        const int dh = tap / 3, dw = tap % 3;
#pragma unroll
        for (int cib = 0; cib < 8; ++cib) {
            i32x4 af[2];
#pragma unroll
            for (int a = 0; a < 2; ++a)
                af[a] = *(const i32x4*)(A_pack +
                    ((size_t)(((tap * 8 + cib) * 8 + wv * 2 + a) * 64 + lane) << 4));
            i32x4 bf[2][2];
#pragma unroll
            for (int nh = 0; nh < 2; ++nh)
#pragma unroll
                for (int row = 0; row < 2; ++row)
                    bf[nh][row] = *(const i32x4*)(slab +
                        ((dh + row) * 66 + (nh * 32 + l31) + dw) * 272 + l5 * 16 + cib * 32);
#pragma unroll
            for (int a = 0; a < 2; ++a)
#pragma unroll
                for (int nh = 0; nh < 2; ++nh)
#pragma unroll
                    for (int row = 0; row < 2; ++row)
                        acc[a][nh][row] = __builtin_amdgcn_mfma_i32_32x32x32_i8(
                            af[a], bf[nh][row], acc[a][nh][row], 0, 0, 0);
        }
    }

    // epilogue: pure coalesced-ish stores (S exact integer as float)
    float* ob = out + ((size_t)(b * 256 + wv * 64)) * N_SP + h0 * 56;
#pragma unroll
    for (int a = 0; a < 2; ++a)
#pragma unroll
        for (int nh = 0; nh < 2; ++nh) {
            const int w = nh * 32 + l31;
            if (w < 56) {
#pragma unroll
                for (int row = 0; row < 2; ++row)
#pragma unroll
                    for (int reg = 0; reg < 16; ++reg) {
                        int corow = (reg & 3) + 8 * (reg >> 2) + 4 * l5;
                        ob[(size_t)(a * 32 + corow) * N_SP + row * 56 + w] =
                            (float)acc[a][nh][row][reg];
                    }
            }
        }
}

// ---------------------------------------------------------------- stats
// grid (256 channels, 8 slices of 4 images). Exact i64/u64 reduction of S;
// 16 atomics per channel total (stats zeroed in prep_weights).
__global__ __launch_bounds__(256) void stats_reduce(const float* __restrict__ out,
                                                    u64* __restrict__ stats) {
    const int c = blockIdx.x;
    const int sl = blockIdx.y;
    const int t = threadIdx.x;
    long long s1 = 0;
    u64 s2 = 0;
    for (int i = t; i < 4 * 784; i += 256) {
        int bl = i / 784, q = i - bl * 784;
        int b = sl * 4 + bl;
        float4 v = ((const float4*)out)[(size_t)(b * 256 + c) * 784 + q];
        int x0 = (int)v.x, x1 = (int)v.y, x2 = (int)v.z, x3 = (int)v.w;
        s1 += x0 + x1 + x2 + x3;
        s2 += (u64)((long long)x0 * x0 + (long long)x1 * x1 +
                    (long long)x2 * x2 + (long long)x3 * x3);
    }
#pragma unroll
    for (int off = 32; off > 0; off >>= 1) {
        s1 += __shfl_down(s1, off);
        s2 += __shfl_down(s2, off);
    }
    __shared__ long long p1[4];
    __shared__ u64 p2[4];
    if ((t & 63) == 0) { p1[t >> 6] = s1; p2[t >> 6] = s2; }
    __syncthreads();
    if (t == 0) {
        atomicAdd(&stats[c], (u64)(p1[0] + p1[1] + p1[2] + p1[3]));
        atomicAdd(&stats[C_OUT + c], p2[0] + p2[1] + p2[2] + p2[3]);
    }
}

// ---------------------------------------------------------------- BN consts
__global__ void make_consts(const u64* __restrict__ stats,
                            const double* __restrict__ alpha,
                            const float* __restrict__ gamma,
                            const float* __restrict__ beta,
                            double* __restrict__ AB) {
    const int c = threadIdx.x;
    const double N = (double)(BATCH * N_SP);
    double s1 = (double)(long long)stats[c];
    double s2 = (double)(long long)stats[C_OUT + c];
    double mu = s1 / N;
    double var = s2 / N - mu * mu;
    double a = alpha[c];
    double vy = a * a * var;
    double scale = (double)gamma[c] / sqrt(vy + 1e-5);
    double A = a * scale;
    double B = (double)beta[c] - A * mu;
    AB[c] = A;
    AB[C_OUT + c] = B;
}

// ---------------------------------------------------------------- finalize
// In-place: d_out holds exact-integer S as float; out = (A*S+B > 0) ? 1 : 0.
__global__ __launch_bounds__(256) void finalize(float* __restrict__ out,
                                                const double* __restrict__ AB) {
    const unsigned i4 = blockIdx.x * 256 + threadIdx.x;   // 0 .. 6422527
    const unsigned e = i4 << 2;                            // element base
    const int c = (int)((e / N_SP) & (C_OUT - 1));         // 3136 | 4 -> c uniform in float4
    const double A = AB[c];
    const double B = AB[C_OUT + c];
    float4 v = ((float4*)out)[i4];
    v.x = (A * (double)v.x + B) > 0.0 ? 1.0f : 0.0f;
    v.y = (A * (double)v.y + B) > 0.0 ? 1.0f : 0.0f;
    v.z = (A * (double)v.z + B) > 0.0 ? 1.0f : 0.0f;
    v.w = (A * (double)v.w + B) > 0.0 ? 1.0f : 0.0f;
    ((float4*)out)[i4] = v;
}

// ---------------------------------------------------------------- launch
extern "C" void kernel_launch(void* const* d_in, const int* in_sizes, int n_in,
                              void* d_out, int out_size, void* d_ws, size_t ws_size,
                              hipStream_t stream) {
    const float* x      = (const float*)d_in[0];
    const float* weight = (const float*)d_in[1];
    const float* bias   = (const float*)d_in[2];   (void)bias;  // cancels in BN
    const float* gamma  = (const float*)d_in[3];
    const float* beta   = (const float*)d_in[4];
    float* out = (float*)d_out;

    char* ws = (char*)d_ws;
    u64*    stats = (u64*)(ws);                 // [512]
    double* alpha = (double*)(ws + 4096);       // [256]
    double* AB    = (double*)(ws + 8192);       // [512]
    char*   A_pack = (char*)(ws + 16384);       // 589,824 B fragment-ordered signs
    char*   xsT   = (char*)(ws + (1 << 20));    // 30,408,704 B padded channel-last signs

    prep_weights<<<C_OUT, 256, 0, stream>>>(weight, A_pack, alpha, stats);
    zero_borders<<<1152, 256, 0, stream>>>(xsT);
    sign_transpose<<<dim3(49, BATCH), 256, 0, stream>>>(x, xsT);
    conv_mfma<<<BATCH * 28, 256, 0, stream>>>(xsT, A_pack, out);
    stats_reduce<<<dim3(C_OUT, 8), 256, 0, stream>>>(out, stats);
    make_consts<<<1, C_OUT, 0, stream>>>(stats, alpha, gamma, beta, AB);
    finalize<<<(out_size / 4) / 256, 256, 0, stream>>>(out, AB);
}